// Round 11
// baseline (159.568 us; speedup 1.0000x reference)
//
#include <hip/hip_runtime.h>
#include <stdint.h>

#define NQ 8

typedef float v2 __attribute__((ext_vector_type(2)));

__device__ __forceinline__ v2 mkv2(float a, float b) { v2 r; r.x = a; r.y = b; return r; }
__device__ __forceinline__ v2 splat(float a)         { v2 r; r.x = a; r.y = a; return r; }
__device__ __forceinline__ v2 swapc(v2 a)            { return __builtin_shufflevector(a, a, 1, 0); }

__device__ __forceinline__ v2 pkfma(v2 a, v2 b, v2 c) {
#if __has_builtin(__builtin_elementwise_fma)
    return __builtin_elementwise_fma(a, b, c);
#else
    return mkv2(__builtin_fmaf(a.x, b.x, c.x), __builtin_fmaf(a.y, b.y, c.y));
#endif
}

// sin/cos of theta (radians) via raw v_sin/v_cos (input in revolutions).
#define INV2PI 0.15915494309189535f
__device__ __forceinline__ float fsinr(float th) { return __builtin_amdgcn_sinf(th * INV2PI); }
__device__ __forceinline__ float fcosr(float th) { return __builtin_amdgcn_cosf(th * INV2PI); }

// ---- cross-lane xor exchange within aligned 32-lane groups ----
// xor1/xor2: DPP quad_perm; xor8: DPP row_ror:8; xor4/xor16: ds_swizzle BitMode.
template<int XM>
__device__ __forceinline__ float sx(float v) {
    if constexpr (XM == 0) return v;
    const int x = __float_as_int(v);
    int r;
    if constexpr (XM == 1)      r = __builtin_amdgcn_update_dpp(0, x, 0xB1,  0xF, 0xF, true);
    else if constexpr (XM == 2) r = __builtin_amdgcn_update_dpp(0, x, 0x4E,  0xF, 0xF, true);
    else if constexpr (XM == 8) r = __builtin_amdgcn_update_dpp(0, x, 0x128, 0xF, 0xF, true);
    else                        r = __builtin_amdgcn_ds_swizzle(x, (XM << 10) | 0x1F);
    return __int_as_float(r);
}
template<int XM>
__device__ __forceinline__ v2 xl(v2 a) {
    if constexpr (XM == 0) return a;
    return mkv2(sx<XM>(a.x), sx<XM>(a.y));
}

__device__ __forceinline__ void swapv(v2& a, v2& b) { v2 t = a; a = b; b = t; }

// Layout: amp index g = i | (laneq<<3); qubit k -> bit k of g.
// Qubits 0..2 = local bits (i in [0,8)), qubits 3..7 = lane bits (laneq in [0,32)).
// Each amp is one v2 (re, im) -> packed f32 ops process re+im together.

// ---- real 2x2 [[a,b],[d,e]] on qubit Q ----
template<int Q>
__device__ __forceinline__ void realGate(v2 (&sv)[8], int laneq,
                                         float a, float b, float d, float e)
{
    if constexpr (Q < 3) {
        constexpr int M = 1 << Q;
        const v2 av = splat(a), bv = splat(b), dv = splat(d), ev = splat(e);
#pragma unroll
        for (int i = 0; i < 8; i++) if (!(i & M)) {
            const int j = i | M;
            v2 x0 = sv[i], x1 = sv[j];
            sv[i] = pkfma(bv, x1, av * x0);
            sv[j] = pkfma(ev, x1, dv * x0);
        }
    } else {
        constexpr int XM = 1 << (Q - 3);
        const int bit = (laneq >> (Q - 3)) & 1;
        const v2 scv = splat(bit ? e : a);   // self coefficient
        const v2 pcv = splat(bit ? d : b);   // partner coefficient
#pragma unroll
        for (int i = 0; i < 8; i++) {
            v2 p = xl<XM>(sv[i]);
            sv[i] = pkfma(pcv, p, scv * sv[i]);
        }
    }
}

// ---- RX: [[c, -i s], [-i s, c]];  -i s * (x+iy) = s*(y, -x) = (s,-s) (.) swap(v) ----
template<int Q>
__device__ __forceinline__ void applyRX(v2 (&sv)[8], int laneq, float c, float s)
{
    const v2 cv = splat(c), sg = mkv2(s, -s);
    if constexpr (Q < 3) {
        constexpr int M = 1 << Q;
#pragma unroll
        for (int i = 0; i < 8; i++) if (!(i & M)) {
            const int j = i | M;
            v2 x0 = sv[i], x1 = sv[j];
            sv[i] = pkfma(sg, swapc(x1), cv * x0);
            sv[j] = pkfma(sg, swapc(x0), cv * x1);
        }
    } else {
        constexpr int XM = 1 << (Q - 3);
#pragma unroll
        for (int i = 0; i < 8; i++) {
            v2 p = xl<XM>(sv[i]);
            sv[i] = pkfma(sg, swapc(p), cv * sv[i]);
        }
    }
}

// ---- RZ: diag(c-is, c+is).  (c∓is)(x+iy) = c*v + (±s,∓s) (.) swap(v) ----
template<int Q>
__device__ __forceinline__ void applyRZ(v2 (&sv)[8], int laneq, float c, float s)
{
    const v2 cv = splat(c);
    const v2 tp = mkv2(s, -s), tm = mkv2(-s, s);
    if constexpr (Q >= 3) {
        const int bit = (laneq >> (Q - 3)) & 1;
        const v2 t = bit ? tm : tp;
#pragma unroll
        for (int i = 0; i < 8; i++)
            sv[i] = pkfma(t, swapc(sv[i]), cv * sv[i]);
    } else {
#pragma unroll
        for (int i = 0; i < 8; i++) {
            const v2 t = ((i >> Q) & 1) ? tm : tp;
            sv[i] = pkfma(t, swapc(sv[i]), cv * sv[i]);
        }
    }
}

// ---- Pauli Z ----
template<int Q>
__device__ __forceinline__ void applyZ(v2 (&sv)[8], int laneq)
{
    if constexpr (Q >= 3) {
        const v2 m = splat(((laneq >> (Q - 3)) & 1) ? -1.f : 1.f);
#pragma unroll
        for (int i = 0; i < 8; i++) sv[i] *= m;
    } else {
#pragma unroll
        for (int i = 0; i < 8; i++) if ((i >> Q) & 1) sv[i] = -sv[i];
    }
}

// ---- Pauli X ----
template<int Q>
__device__ __forceinline__ void applyX(v2 (&sv)[8], int laneq)
{
    if constexpr (Q < 3) {
        constexpr int M = 1 << Q;
#pragma unroll
        for (int i = 0; i < 8; i++) if (!(i & M))
            swapv(sv[i], sv[i | M]);
    } else {
        constexpr int XM = 1 << (Q - 3);
#pragma unroll
        for (int i = 0; i < 8; i++)
            sv[i] = xl<XM>(sv[i]);
    }
}

// ---- Pauli Y: out(bit0) = -i*x1 = (y1, -x1);  out(bit1) = i*x0 = (-y0, x0) ----
template<int Q>
__device__ __forceinline__ void applyY(v2 (&sv)[8], int laneq)
{
    const v2 PJ = mkv2(1.f, -1.f), NJ = mkv2(-1.f, 1.f);
    if constexpr (Q < 3) {
        constexpr int M = 1 << Q;
#pragma unroll
        for (int i = 0; i < 8; i++) if (!(i & M)) {
            const int j = i | M;
            v2 x0 = sv[i], x1 = sv[j];
            sv[i] = swapc(x1) * PJ;
            sv[j] = swapc(x0) * NJ;
        }
    } else {
        constexpr int XM = 1 << (Q - 3);
        const int bit = (laneq >> (Q - 3)) & 1;
        const v2 mj = bit ? NJ : PJ;
#pragma unroll
        for (int i = 0; i < 8; i++) {
            v2 p = xl<XM>(sv[i]);
            sv[i] = swapc(p) * mj;
        }
    }
}

// ---- CZ(C,T): sign flip when both bits set — shuffle-free ----
template<int C, int T>
__device__ __forceinline__ void applyCZ(v2 (&sv)[8], int laneq)
{
#pragma unroll
    for (int i = 0; i < 8; i++) {
        const int g = i | (laneq << 3);
        const bool f = (((g >> C) & (g >> T)) & 1) != 0;
        sv[i] = f ? -sv[i] : sv[i];
    }
}

// ---- controlled bit-flip: new[g] = old[g ^ M] when (g & CM) == CM ----
template<int CM, int M>
__device__ __forceinline__ void applyCPerm(v2 (&sv)[8], int laneq)
{
    constexpr int LX  = M >> 3;    // target in lane bits -> exchange mask
    constexpr int PL  = M & 7;     // target in local bits
    constexpr int CML = CM & 7;    // controls in local bits
    constexpr int CMH = CM >> 3;   // controls in lane bits
    if constexpr (LX != 0) {
#pragma unroll
        for (int i = 0; i < 8; i++) {
            if ((i & CML) == CML) {
                v2 p = xl<LX>(sv[i]);
                if constexpr (CMH != 0) {
                    const bool c = (laneq & CMH) == CMH;
                    sv[i] = c ? p : sv[i];
                } else {
                    sv[i] = p;
                }
            }
        }
    } else {
#pragma unroll
        for (int i = 0; i < 8; i++) {
            if (!(i & PL) && ((i & CML) == CML)) {
                const int j = i | PL;
                if constexpr (CMH != 0) {
                    const bool c = (laneq & CMH) == CMH;
                    v2 t0 = sv[i];
                    sv[i] = c ? sv[j] : sv[i];
                    sv[j] = c ? t0 : sv[j];
                } else {
                    swapv(sv[i], sv[j]);
                }
            }
        }
    }
}

// ---- CSWAP(C; T1,T2): swap bits T1,T2 when control set ----
template<int C, int T1, int T2>
__device__ __forceinline__ void applyCSWAP(v2 (&sv)[8], int laneq)
{
    constexpr int M  = (1 << T1) | (1 << T2);
    constexpr int LX = M >> 3;
    constexpr int PL = M & 7;

    if constexpr (LX == 0) {
        // both targets local: representative i has T1-bit=1, T2-bit=0
#pragma unroll
        for (int i = 0; i < 8; i++) {
            if (((i >> T1) & 1) && !((i >> T2) & 1)) {
                bool skip = false;
                if constexpr (C < 3) { if (!((i >> C) & 1)) skip = true; }
                if (!skip) {
                    const int j = i ^ PL;
                    if constexpr (C >= 3) {
                        const bool c = ((laneq >> (C - 3)) & 1) != 0;
                        v2 t0 = sv[i];
                        sv[i] = c ? sv[j] : sv[i];
                        sv[j] = c ? t0 : sv[j];
                    } else {
                        swapv(sv[i], sv[j]);
                    }
                }
            }
        }
    } else if constexpr (PL == 0) {
        // both targets in lane bits
        bool c = ((((laneq >> (T1 - 3)) ^ (laneq >> (T2 - 3))) & 1) != 0);
        if constexpr (C >= 3) c = c && (((laneq >> (C - 3)) & 1) != 0);
#pragma unroll
        for (int i = 0; i < 8; i++) {
            bool skip = false;
            if constexpr (C < 3) { if (!((i >> C) & 1)) skip = true; }
            if (!skip) {
                v2 p = xl<LX>(sv[i]);
                sv[i] = c ? p : sv[i];
            }
        }
    } else {
        // mixed: one local target (PL), one lane target (LX)
        constexpr int TL = (PL == (1 << T1)) ? T2 : T1;    // lane-resident target
        const bool laneT = ((laneq >> (TL - 3)) & 1) != 0;
        bool cc = true;
        if constexpr (C >= 3) cc = ((laneq >> (C - 3)) & 1) != 0;
#pragma unroll
        for (int i = 0; i < 8; i++) {
            if (!(i & PL)) {
                bool skip = false;
                if constexpr (C < 3) { if (!((i >> C) & 1)) skip = true; }
                if (!skip) {
                    const int j = i | PL;
                    // read partner-lane values before any write (lockstep)
                    v2 a = xl<LX>(sv[j]);
                    v2 b = xl<LX>(sv[i]);
                    const bool ci = cc && laneT;
                    const bool cj = cc && !laneT;
                    sv[i] = ci ? a : sv[i];
                    sv[j] = cj ? b : sv[j];
                }
            }
        }
    }
}

// ---- one node step; node N compile-time; design bits passed as packed scalars ----
template<int N>
__device__ __forceinline__ void nodeStep(v2 (&sv)[8], int laneq,
                                         const float* fvp,                 // LDS, 8 angles
                                         const float* __restrict__ qp,
                                         int layer,
                                         int dryL, int drotL, int dg2L)
{
    constexpr int N1 = (N + 1) & 7;
    constexpr int N2 = (N + 2) & 7;
    constexpr int SL = N & 3;

    // 1) per-sample RY(feats[b, N]) — angle from LDS broadcast, sincos at use
    if ((dryL >> SL) & 1) {
        const float th = fvp[N] * 0.5f;
        const float c = fcosr(th), s = fsinr(th);
        realGate<N>(sv, laneq, c, -s, s, c);
    }

    // 2) trainable rotation — uniform scalar load at use
    const int rot = (drotL >> (2 * SL)) & 3;
    if (rot < 3) {
        const float th = qp[layer * NQ + N] * 0.5f;
        const float c = fcosr(th), s = fsinr(th);
        if (rot == 0)      applyRX<N>(sv, laneq, c, s);
        else if (rot == 1) realGate<N>(sv, laneq, c, -s, s, c);
        else               applyRZ<N>(sv, laneq, c, s);
    }

    // 3) entangling / extra gate
    const int g2 = (dg2L >> (4 * SL)) & 15;
    switch (g2) {
        case 1: {
            const float r = 0.70710678118654752f;
            realGate<N>(sv, laneq, r, r, r, -r);
        } break;
        case 2: applyX<N>(sv, laneq); break;
        case 3: applyY<N>(sv, laneq); break;
        case 4: applyZ<N>(sv, laneq); break;
        case 5: applyCPerm<(1 << N), (1 << N1)>(sv, laneq); break;
        case 6: applyCSWAP<N, N1, N2>(sv, laneq); break;
        case 7: applyCPerm<(1 << N) | (1 << N1), (1 << N2)>(sv, laneq); break;
        case 8: applyCZ<N, N1>(sv, laneq); break;
        default: break;
    }
}

__global__ __launch_bounds__(256, 4) void qsim_kernel(
    const float* __restrict__ feats,    // [B, 8]
    const float* __restrict__ qp,       // [48]
    const int* __restrict__ dry,        // [24]
    const int* __restrict__ drot,       // [24]
    const int* __restrict__ dg2,        // [24]
    float* __restrict__ out,            // [B, 8]
    int B)
{
    __shared__ float lds_fv[8][8];      // [group][angle], 256 B

    const int laneq = threadIdx.x & 31;                       // lane within element group
    const int grp   = threadIdx.x >> 5;                       // group within block (0..7)
    const int b     = blockIdx.x * 8 + grp;                   // batch element

    // stage this element's 8 RY angles into LDS (written and read within one wave)
    if (laneq < 8)
        lds_fv[grp][laneq] = feats[(size_t)b * NQ + laneq];
    const float* fvp = &lds_fv[grp][0];

    // ---- pack the (uniform) design into SGPRs via readfirstlane ----
    uint32_t dryP = 0;
    uint64_t drotP = 0;
    uint32_t g2P0 = 0, g2P1 = 0, g2P2 = 0;
#pragma unroll
    for (int k = 0; k < 24; k++) {
        dryP  |= (uint32_t)(__builtin_amdgcn_readfirstlane(dry[k]) & 1) << k;
        drotP |= (uint64_t)(__builtin_amdgcn_readfirstlane(drot[k]) & 3) << (2 * k);
    }
#pragma unroll
    for (int k = 0; k < 8; k++) {
        g2P0 |= (uint32_t)(__builtin_amdgcn_readfirstlane(dg2[k])      & 15) << (4 * k);
        g2P1 |= (uint32_t)(__builtin_amdgcn_readfirstlane(dg2[8 + k])  & 15) << (4 * k);
        g2P2 |= (uint32_t)(__builtin_amdgcn_readfirstlane(dg2[16 + k]) & 15) << (4 * k);
    }

    // H^8 |0> = uniform amplitude 1/16
    v2 sv[8];
#pragma unroll
    for (int i = 0; i < 8; i++) sv[i] = mkv2(0.0625f, 0.f);

#pragma unroll 1
    for (int layer = 0; layer < 6; layer++) {
        // per-layer design slice (scalar shifts, no memory)
        const int dryL  = (int)((dryP >> (layer * 4)) & 0xF);
        const int drotL = (int)((drotP >> (layer * 8)) & 0xFF);
        const uint32_t g2w = (layer >= 4) ? g2P2 : ((layer >= 2) ? g2P1 : g2P0);
        const int dg2L  = (int)((g2w >> ((layer & 1) * 16)) & 0xFFFF);

        nodeStep<0>(sv, laneq, fvp, qp, layer, dryL, drotL, dg2L);
        nodeStep<1>(sv, laneq, fvp, qp, layer, dryL, drotL, dg2L);
        nodeStep<2>(sv, laneq, fvp, qp, layer, dryL, drotL, dg2L);
        nodeStep<3>(sv, laneq, fvp, qp, layer, dryL, drotL, dg2L);
        nodeStep<4>(sv, laneq, fvp, qp, layer, dryL, drotL, dg2L);
        nodeStep<5>(sv, laneq, fvp, qp, layer, dryL, drotL, dg2L);
        nodeStep<6>(sv, laneq, fvp, qp, layer, dryL, drotL, dg2L);
        nodeStep<7>(sv, laneq, fvp, qp, layer, dryL, drotL, dg2L);
    }

    // ---- epilogue: <Z_q> ----
    float tot = 0.f, s0 = 0.f, s1 = 0.f, s2 = 0.f;
#pragma unroll
    for (int i = 0; i < 8; i++) {
        const float p = __builtin_fmaf(sv[i].x, sv[i].x, sv[i].y * sv[i].y);
        tot += p;
        if (!(i & 1)) s0 += p;
        if (!(i & 2)) s1 += p;
        if (!(i & 4)) s2 += p;
    }
    float e[3] = { 2.f * s0 - tot, 2.f * s1 - tot, 2.f * s2 - tot };

    // sum e[0..2] over the 32-lane group
#pragma unroll
    for (int q = 0; q < 3; q++) {
        e[q] += sx<1>(e[q]);
        e[q] += sx<2>(e[q]);
        e[q] += sx<4>(e[q]);
        e[q] += sx<8>(e[q]);
        e[q] += sx<16>(e[q]);
    }
    // FWHT on tot: after 5 stages, laneq = (1<<k) holds <Z_{3+k}>
    { float pv = sx<1>(tot);  tot = (laneq & 1)  ? (pv - tot) : (pv + tot); }
    { float pv = sx<2>(tot);  tot = (laneq & 2)  ? (pv - tot) : (pv + tot); }
    { float pv = sx<4>(tot);  tot = (laneq & 4)  ? (pv - tot) : (pv + tot); }
    { float pv = sx<8>(tot);  tot = (laneq & 8)  ? (pv - tot) : (pv + tot); }
    { float pv = sx<16>(tot); tot = (laneq & 16) ? (pv - tot) : (pv + tot); }

    float* ob = out + (size_t)b * NQ;
    if (laneq == 0) { ob[0] = e[0]; ob[1] = e[1]; ob[2] = e[2]; }
    if (laneq && !(laneq & (laneq - 1)))          // laneq in {1,2,4,8,16}
        ob[3 + __builtin_ctz(laneq)] = tot;
}

extern "C" void kernel_launch(void* const* d_in, const int* in_sizes, int n_in,
                              void* d_out, int out_size, void* d_ws, size_t ws_size,
                              hipStream_t stream)
{
    (void)n_in; (void)out_size; (void)d_ws; (void)ws_size;
    const float* feats   = (const float*)d_in[0];
    const float* qparams = (const float*)d_in[1];
    const int* dry       = (const int*)d_in[2];
    const int* drot      = (const int*)d_in[3];
    const int* dg2       = (const int*)d_in[4];
    float* out           = (float*)d_out;

    const int B = in_sizes[0] / NQ;             // 16384
    const int blocks = (B + 7) / 8;             // 8 elements per 256-thread block
    qsim_kernel<<<blocks, 256, 0, stream>>>(feats, qparams, dry, drot, dg2, out, B);
}

// Round 12
// 122.419 us; speedup vs baseline: 1.3035x; 1.3035x over previous
//
#include <hip/hip_runtime.h>
#include <stdint.h>

#define NQ 8

// sin/cos of theta (radians) via raw v_sin/v_cos (input in revolutions).
#define INV2PI 0.15915494309189535f
__device__ __forceinline__ float fsinr(float th) { return __builtin_amdgcn_sinf(th * INV2PI); }
__device__ __forceinline__ float fcosr(float th) { return __builtin_amdgcn_cosf(th * INV2PI); }

// ---- cross-lane xor exchange within aligned 32-lane groups ----
// xor1/xor2: DPP quad_perm; xor8: DPP row_ror:8 (within 16-lane rows, ror8 == xor8).
// xor4/xor16: ds_swizzle BitMode (operates within 32-lane groups).
template<int XM>
__device__ __forceinline__ float sx(float v) {
    if constexpr (XM == 0) return v;
    const int x = __float_as_int(v);
    int r;
    if constexpr (XM == 1)      r = __builtin_amdgcn_update_dpp(0, x, 0xB1,  0xF, 0xF, true); // quad [1,0,3,2]
    else if constexpr (XM == 2) r = __builtin_amdgcn_update_dpp(0, x, 0x4E,  0xF, 0xF, true); // quad [2,3,0,1]
    else if constexpr (XM == 8) r = __builtin_amdgcn_update_dpp(0, x, 0x128, 0xF, 0xF, true); // row_ror:8
    else                        r = __builtin_amdgcn_ds_swizzle(x, (XM << 10) | 0x1F);        // 4, 16
    return __int_as_float(r);
}

__device__ __forceinline__ void swapf(float& a, float& b) { float t = a; a = b; b = t; }

// Layout: amp index g = i | (laneq<<3); qubit k -> bit k of g.
// Qubits 0..2 = local bits (i in [0,8)), qubits 3..7 = lane bits (laneq in [0,32)).

// ---- real 2x2 [[a,b],[d,e]] on qubit Q ----
template<int Q>
__device__ __forceinline__ void realGate(float (&sr)[8], float (&si)[8], int laneq,
                                         float a, float b, float d, float e)
{
    if constexpr (Q < 3) {
        constexpr int M = 1 << Q;
#pragma unroll
        for (int i = 0; i < 8; i++) if (!(i & M)) {
            const int j = i | M;
            float x0r = sr[i], x0i = si[i], x1r = sr[j], x1i = si[j];
            sr[i] = a * x0r + b * x1r;  si[i] = a * x0i + b * x1i;
            sr[j] = d * x0r + e * x1r;  si[j] = d * x0i + e * x1i;
        }
    } else {
        constexpr int XM = 1 << (Q - 3);
        const int bit = (laneq >> (Q - 3)) & 1;
        const float sc = bit ? e : a;   // self coefficient
        const float pc = bit ? d : b;   // partner coefficient
#pragma unroll
        for (int i = 0; i < 8; i++) {
            float pr = sx<XM>(sr[i]);
            float pi = sx<XM>(si[i]);
            sr[i] = sc * sr[i] + pc * pr;
            si[i] = sc * si[i] + pc * pi;
        }
    }
}

// ---- RX: [[c, -i s], [-i s, c]] ----
template<int Q>
__device__ __forceinline__ void applyRX(float (&sr)[8], float (&si)[8], int laneq,
                                        float c, float s)
{
    if constexpr (Q < 3) {
        constexpr int M = 1 << Q;
#pragma unroll
        for (int i = 0; i < 8; i++) if (!(i & M)) {
            const int j = i | M;
            float x0r = sr[i], x0i = si[i], x1r = sr[j], x1i = si[j];
            sr[i] = c * x0r + s * x1i;  si[i] = c * x0i - s * x1r;
            sr[j] = c * x1r + s * x0i;  si[j] = c * x1i - s * x0r;
        }
    } else {
        constexpr int XM = 1 << (Q - 3);
#pragma unroll
        for (int i = 0; i < 8; i++) {
            float pr = sx<XM>(sr[i]);
            float pi = sx<XM>(si[i]);
            float nr = c * sr[i] + s * pi;
            float ni = c * si[i] - s * pr;
            sr[i] = nr; si[i] = ni;
        }
    }
}

// ---- RZ: diag(c - i s, c + i s) — shuffle-free ----
template<int Q>
__device__ __forceinline__ void applyRZ(float (&sr)[8], float (&si)[8], int laneq,
                                        float c, float s)
{
    if constexpr (Q >= 3) {
        const int bit = (laneq >> (Q - 3)) & 1;
        const float t = bit ? -s : s;
#pragma unroll
        for (int i = 0; i < 8; i++) {
            float nr = c * sr[i] + t * si[i];
            float ni = c * si[i] - t * sr[i];
            sr[i] = nr; si[i] = ni;
        }
    } else {
#pragma unroll
        for (int i = 0; i < 8; i++) {
            const float t = ((i >> Q) & 1) ? -s : s;
            float nr = c * sr[i] + t * si[i];
            float ni = c * si[i] - t * sr[i];
            sr[i] = nr; si[i] = ni;
        }
    }
}

// ---- Pauli Z ----
template<int Q>
__device__ __forceinline__ void applyZ(float (&sr)[8], float (&si)[8], int laneq)
{
    if constexpr (Q >= 3) {
        const bool f = ((laneq >> (Q - 3)) & 1) != 0;
#pragma unroll
        for (int i = 0; i < 8; i++) {
            sr[i] = f ? -sr[i] : sr[i];
            si[i] = f ? -si[i] : si[i];
        }
    } else {
#pragma unroll
        for (int i = 0; i < 8; i++) if ((i >> Q) & 1) {
            sr[i] = -sr[i]; si[i] = -si[i];
        }
    }
}

// ---- Pauli X ----
template<int Q>
__device__ __forceinline__ void applyX(float (&sr)[8], float (&si)[8], int laneq)
{
    if constexpr (Q < 3) {
        constexpr int M = 1 << Q;
#pragma unroll
        for (int i = 0; i < 8; i++) if (!(i & M)) {
            swapf(sr[i], sr[i | M]); swapf(si[i], si[i | M]);
        }
    } else {
        constexpr int XM = 1 << (Q - 3);
#pragma unroll
        for (int i = 0; i < 8; i++) {
            sr[i] = sx<XM>(sr[i]);
            si[i] = sx<XM>(si[i]);
        }
    }
}

// ---- Pauli Y: [[0,-i],[i,0]] ----
template<int Q>
__device__ __forceinline__ void applyY(float (&sr)[8], float (&si)[8], int laneq)
{
    if constexpr (Q < 3) {
        constexpr int M = 1 << Q;
#pragma unroll
        for (int i = 0; i < 8; i++) if (!(i & M)) {
            const int j = i | M;
            float x0r = sr[i], x0i = si[i], x1r = sr[j], x1i = si[j];
            sr[i] = x1i;  si[i] = -x1r;
            sr[j] = -x0i; si[j] = x0r;
        }
    } else {
        constexpr int XM = 1 << (Q - 3);
        const int bit = (laneq >> (Q - 3)) & 1;
#pragma unroll
        for (int i = 0; i < 8; i++) {
            float pr = sx<XM>(sr[i]);
            float pi = sx<XM>(si[i]);
            sr[i] = bit ? -pi : pi;
            si[i] = bit ? pr : -pr;
        }
    }
}

// ---- CZ(C,T): sign flip when both bits set — shuffle-free ----
template<int C, int T>
__device__ __forceinline__ void applyCZ(float (&sr)[8], float (&si)[8], int laneq)
{
#pragma unroll
    for (int i = 0; i < 8; i++) {
        const int g = i | (laneq << 3);
        const bool f = (((g >> C) & (g >> T)) & 1) != 0;
        sr[i] = f ? -sr[i] : sr[i];
        si[i] = f ? -si[i] : si[i];
    }
}

// ---- controlled bit-flip: new[g] = old[g ^ M] when (g & CM) == CM ----
template<int CM, int M>
__device__ __forceinline__ void applyCPerm(float (&sr)[8], float (&si)[8], int laneq)
{
    constexpr int LX  = M >> 3;    // target in lane bits -> exchange mask
    constexpr int PL  = M & 7;     // target in local bits
    constexpr int CML = CM & 7;    // controls in local bits
    constexpr int CMH = CM >> 3;   // controls in lane bits
    if constexpr (LX != 0) {
#pragma unroll
        for (int i = 0; i < 8; i++) {
            if ((i & CML) == CML) {
                float pr = sx<LX>(sr[i]);
                float pi = sx<LX>(si[i]);
                if constexpr (CMH != 0) {
                    const bool c = (laneq & CMH) == CMH;
                    sr[i] = c ? pr : sr[i];
                    si[i] = c ? pi : si[i];
                } else {
                    sr[i] = pr; si[i] = pi;
                }
            }
        }
    } else {
#pragma unroll
        for (int i = 0; i < 8; i++) {
            if (!(i & PL) && ((i & CML) == CML)) {
                const int j = i | PL;
                if constexpr (CMH != 0) {
                    const bool c = (laneq & CMH) == CMH;
                    float t0r = sr[i], t0i = si[i];
                    sr[i] = c ? sr[j] : sr[i];  si[i] = c ? si[j] : si[i];
                    sr[j] = c ? t0r : sr[j];    si[j] = c ? t0i : si[j];
                } else {
                    swapf(sr[i], sr[j]); swapf(si[i], si[j]);
                }
            }
        }
    }
}

// ---- CSWAP(C; T1,T2): swap bits T1,T2 when control set ----
template<int C, int T1, int T2>
__device__ __forceinline__ void applyCSWAP(float (&sr)[8], float (&si)[8], int laneq)
{
    constexpr int M  = (1 << T1) | (1 << T2);
    constexpr int LX = M >> 3;
    constexpr int PL = M & 7;

    if constexpr (LX == 0) {
        // both targets local: representative i has T1-bit=1, T2-bit=0
#pragma unroll
        for (int i = 0; i < 8; i++) {
            if (((i >> T1) & 1) && !((i >> T2) & 1)) {
                bool skip = false;
                if constexpr (C < 3) { if (!((i >> C) & 1)) skip = true; }
                if (!skip) {
                    const int j = i ^ PL;
                    if constexpr (C >= 3) {
                        const bool c = ((laneq >> (C - 3)) & 1) != 0;
                        float t0r = sr[i], t0i = si[i];
                        sr[i] = c ? sr[j] : sr[i];  si[i] = c ? si[j] : si[i];
                        sr[j] = c ? t0r : sr[j];    si[j] = c ? t0i : si[j];
                    } else {
                        swapf(sr[i], sr[j]); swapf(si[i], si[j]);
                    }
                }
            }
        }
    } else if constexpr (PL == 0) {
        // both targets in lane bits
        bool c = ((((laneq >> (T1 - 3)) ^ (laneq >> (T2 - 3))) & 1) != 0);
        if constexpr (C >= 3) c = c && (((laneq >> (C - 3)) & 1) != 0);
#pragma unroll
        for (int i = 0; i < 8; i++) {
            bool skip = false;
            if constexpr (C < 3) { if (!((i >> C) & 1)) skip = true; }
            if (!skip) {
                float pr = sx<LX>(sr[i]);
                float pi = sx<LX>(si[i]);
                sr[i] = c ? pr : sr[i];
                si[i] = c ? pi : si[i];
            }
        }
    } else {
        // mixed: one local target (PL), one lane target (LX)
        constexpr int TL = (PL == (1 << T1)) ? T2 : T1;    // lane-resident target
        const bool laneT = ((laneq >> (TL - 3)) & 1) != 0;
        bool cc = true;
        if constexpr (C >= 3) cc = ((laneq >> (C - 3)) & 1) != 0;
#pragma unroll
        for (int i = 0; i < 8; i++) {
            if (!(i & PL)) {
                bool skip = false;
                if constexpr (C < 3) { if (!((i >> C) & 1)) skip = true; }
                if (!skip) {
                    const int j = i | PL;
                    // read partner-lane values before any write (lockstep)
                    float a_r = sx<LX>(sr[j]), a_i = sx<LX>(si[j]);  // -> sr[i]
                    float b_r = sx<LX>(sr[i]), b_i = sx<LX>(si[i]);  // -> sr[j]
                    const bool ci = cc && laneT;
                    const bool cj = cc && !laneT;
                    sr[i] = ci ? a_r : sr[i];  si[i] = ci ? a_i : si[i];
                    sr[j] = cj ? b_r : sr[j];  si[j] = cj ? b_i : si[j];
                }
            }
        }
    }
}

// ---- one node step; node N compile-time; design bits passed as packed scalars ----
// dryL: 4 bits (node&3), drotL: 8 bits (2 per node&3), dg2L: 16 bits (4 per node&3)
template<int N>
__device__ __forceinline__ void nodeStep(float (&sr)[8], float (&si)[8], int laneq,
                                         const float* fvp,                 // LDS, 8 angles
                                         const float* __restrict__ qp,
                                         int layer,
                                         int dryL, int drotL, int dg2L)
{
    constexpr int N1 = (N + 1) & 7;
    constexpr int N2 = (N + 2) & 7;
    constexpr int SL = N & 3;

    // 1) per-sample RY(feats[b, N]) — angle from LDS broadcast, sincos at use
    if ((dryL >> SL) & 1) {
        const float th = fvp[N] * 0.5f;
        const float c = fcosr(th), s = fsinr(th);
        realGate<N>(sr, si, laneq, c, -s, s, c);
    }

    // 2) trainable rotation — uniform scalar load at use
    const int rot = (drotL >> (2 * SL)) & 3;
    if (rot < 3) {
        const float th = qp[layer * NQ + N] * 0.5f;
        const float c = fcosr(th), s = fsinr(th);
        if (rot == 0)      applyRX<N>(sr, si, laneq, c, s);
        else if (rot == 1) realGate<N>(sr, si, laneq, c, -s, s, c);
        else               applyRZ<N>(sr, si, laneq, c, s);
    }

    // 3) entangling / extra gate
    const int g2 = (dg2L >> (4 * SL)) & 15;
    switch (g2) {
        case 1: {
            const float r = 0.70710678118654752f;
            realGate<N>(sr, si, laneq, r, r, r, -r);
        } break;
        case 2: applyX<N>(sr, si, laneq); break;
        case 3: applyY<N>(sr, si, laneq); break;
        case 4: applyZ<N>(sr, si, laneq); break;
        case 5: applyCPerm<(1 << N), (1 << N1)>(sr, si, laneq); break;
        case 6: applyCSWAP<N, N1, N2>(sr, si, laneq); break;
        case 7: applyCPerm<(1 << N) | (1 << N1), (1 << N2)>(sr, si, laneq); break;
        case 8: applyCZ<N, N1>(sr, si, laneq); break;
        default: break;
    }
}

__global__ __launch_bounds__(256, 4) void qsim_kernel(
    const float* __restrict__ feats,    // [B, 8]
    const float* __restrict__ qp,       // [48]
    const int* __restrict__ dry,        // [24]
    const int* __restrict__ drot,       // [24]
    const int* __restrict__ dg2,        // [24]
    float* __restrict__ out,            // [B, 8]
    int B)
{
    __shared__ float lds_fv[8][8];      // [group][angle], 256 B

    const int laneq = threadIdx.x & 31;                       // lane within element group
    const int grp   = threadIdx.x >> 5;                       // group within block (0..7)
    const int b     = blockIdx.x * 8 + grp;                   // batch element

    // stage this element's 8 RY angles into LDS (written and read within one wave)
    if (laneq < 8)
        lds_fv[grp][laneq] = feats[(size_t)b * NQ + laneq];
    const float* fvp = &lds_fv[grp][0];

    // ---- pack the (uniform) design into SGPRs via readfirstlane ----
    uint32_t dryP = 0;
    uint64_t drotP = 0;
    uint32_t g2P0 = 0, g2P1 = 0, g2P2 = 0;
#pragma unroll
    for (int k = 0; k < 24; k++) {
        dryP  |= (uint32_t)(__builtin_amdgcn_readfirstlane(dry[k]) & 1) << k;
        drotP |= (uint64_t)(__builtin_amdgcn_readfirstlane(drot[k]) & 3) << (2 * k);
    }
#pragma unroll
    for (int k = 0; k < 8; k++) {
        g2P0 |= (uint32_t)(__builtin_amdgcn_readfirstlane(dg2[k])      & 15) << (4 * k);
        g2P1 |= (uint32_t)(__builtin_amdgcn_readfirstlane(dg2[8 + k])  & 15) << (4 * k);
        g2P2 |= (uint32_t)(__builtin_amdgcn_readfirstlane(dg2[16 + k]) & 15) << (4 * k);
    }

    // H^8 |0> = uniform amplitude 1/16
    float sr[8], si[8];
#pragma unroll
    for (int i = 0; i < 8; i++) { sr[i] = 0.0625f; si[i] = 0.0f; }

#pragma unroll 1
    for (int layer = 0; layer < 6; layer++) {
        // per-layer design slice (scalar shifts, no memory)
        const int dryL  = (int)((dryP >> (layer * 4)) & 0xF);
        const int drotL = (int)((drotP >> (layer * 8)) & 0xFF);
        const uint32_t g2w = (layer >= 4) ? g2P2 : ((layer >= 2) ? g2P1 : g2P0);
        const int dg2L  = (int)((g2w >> ((layer & 1) * 16)) & 0xFFFF);

        nodeStep<0>(sr, si, laneq, fvp, qp, layer, dryL, drotL, dg2L);
        nodeStep<1>(sr, si, laneq, fvp, qp, layer, dryL, drotL, dg2L);
        nodeStep<2>(sr, si, laneq, fvp, qp, layer, dryL, drotL, dg2L);
        nodeStep<3>(sr, si, laneq, fvp, qp, layer, dryL, drotL, dg2L);
        nodeStep<4>(sr, si, laneq, fvp, qp, layer, dryL, drotL, dg2L);
        nodeStep<5>(sr, si, laneq, fvp, qp, layer, dryL, drotL, dg2L);
        nodeStep<6>(sr, si, laneq, fvp, qp, layer, dryL, drotL, dg2L);
        nodeStep<7>(sr, si, laneq, fvp, qp, layer, dryL, drotL, dg2L);
    }

    // ---- epilogue: <Z_q> ----
    float tot = 0.f, s0 = 0.f, s1 = 0.f, s2 = 0.f;
#pragma unroll
    for (int i = 0; i < 8; i++) {
        float p = sr[i] * sr[i] + si[i] * si[i];
        tot += p;
        if (!(i & 1)) s0 += p;
        if (!(i & 2)) s1 += p;
        if (!(i & 4)) s2 += p;
    }
    float e[3] = { 2.f * s0 - tot, 2.f * s1 - tot, 2.f * s2 - tot };

    // sum e[0..2] over the 32-lane group
#pragma unroll
    for (int q = 0; q < 3; q++) {
        e[q] += sx<1>(e[q]);
        e[q] += sx<2>(e[q]);
        e[q] += sx<4>(e[q]);
        e[q] += sx<8>(e[q]);
        e[q] += sx<16>(e[q]);
    }
    // FWHT on tot: after 5 stages, laneq = (1<<k) holds <Z_{3+k}>
    { float pv = sx<1>(tot);  tot = (laneq & 1)  ? (pv - tot) : (pv + tot); }
    { float pv = sx<2>(tot);  tot = (laneq & 2)  ? (pv - tot) : (pv + tot); }
    { float pv = sx<4>(tot);  tot = (laneq & 4)  ? (pv - tot) : (pv + tot); }
    { float pv = sx<8>(tot);  tot = (laneq & 8)  ? (pv - tot) : (pv + tot); }
    { float pv = sx<16>(tot); tot = (laneq & 16) ? (pv - tot) : (pv + tot); }

    float* ob = out + (size_t)b * NQ;
    if (laneq == 0) { ob[0] = e[0]; ob[1] = e[1]; ob[2] = e[2]; }
    if (laneq && !(laneq & (laneq - 1)))          // laneq in {1,2,4,8,16}
        ob[3 + __builtin_ctz(laneq)] = tot;
}

extern "C" void kernel_launch(void* const* d_in, const int* in_sizes, int n_in,
                              void* d_out, int out_size, void* d_ws, size_t ws_size,
                              hipStream_t stream)
{
    (void)n_in; (void)out_size; (void)d_ws; (void)ws_size;
    const float* feats   = (const float*)d_in[0];
    const float* qparams = (const float*)d_in[1];
    const int* dry       = (const int*)d_in[2];
    const int* drot      = (const int*)d_in[3];
    const int* dg2       = (const int*)d_in[4];
    float* out           = (float*)d_out;

    const int B = in_sizes[0] / NQ;             // 16384
    const int blocks = (B + 7) / 8;             // 8 elements per 256-thread block
    qsim_kernel<<<blocks, 256, 0, stream>>>(feats, qparams, dry, drot, dg2, out, B);
}